// Round 7
// baseline (369.097 us; speedup 1.0000x reference)
//
#include <hip/hip_runtime.h>
#include <math.h>

typedef float f32x4 __attribute__((ext_vector_type(4)));
typedef __bf16 bf16x8 __attribute__((ext_vector_type(8)));

// ---------------------------------------------------------------------------
// CSR row offsets from sorted self_fea_idx. row_start[N] = M.
// ---------------------------------------------------------------------------
__global__ void build_row_start(const int* __restrict__ self_idx,
                                int* __restrict__ row_start, int M, int N) {
  int i = blockIdx.x * blockDim.x + threadIdx.x;
  if (i >= M) return;
  int cur = self_idx[i];
  int prev = (i == 0) ? -1 : self_idx[i - 1];
  for (int j = prev + 1; j <= cur; ++j) row_start[j] = i;
  if (i == M - 1) {
    for (int j = cur + 1; j <= N; ++j) row_start[j] = M;
  }
}

// ---------------------------------------------------------------------------
// Phase A: per-atom precompute of layer-1 halves (bf16 in ws) and a
// B-frag-packed copy of W2.
//   U'[a][d] = sum_k X[a][k]*W1[k][d] + b1[d]
//   Y [a][d] = sum_k X[a][k]*W1[64+k][d]
//   W2pack[(ks*4+c)*64 + lane][0..7] = W2[32ks+8g+j][16c+r16], lane=16g+r16
// ---------------------------------------------------------------------------
__global__ __launch_bounds__(256, 2)
void precompute_uy(const float* __restrict__ atom_fea,
                   const float* __restrict__ W1,
                   const float* __restrict__ b1,
                   const float* __restrict__ W2,
                   __bf16* __restrict__ Ub, __bf16* __restrict__ Yb,
                   __bf16* __restrict__ W2pack, int N) {
  const int lane = threadIdx.x & 63;
  const int r16 = lane & 15, g = lane >> 4;
  const int wid = (blockIdx.x * blockDim.x + threadIdx.x) >> 6;
  const int nw = (gridDim.x * blockDim.x) >> 6;

  if (wid == 0) {  // pack W2 into B-frag order (8 KB, once)
#pragma unroll
    for (int ks = 0; ks < 2; ++ks)
#pragma unroll
      for (int c = 0; c < 4; ++c) {
        bf16x8 t;
#pragma unroll
        for (int jj = 0; jj < 8; ++jj)
          t[jj] = (__bf16)W2[(size_t)(32 * ks + 8 * g + jj) * 64 + 16 * c + r16];
        *(bf16x8*)(W2pack + ((size_t)(ks * 4 + c) * 64 + lane) * 8) = t;
      }
  }

  bf16x8 wt[2][4], wb[2][4];
#pragma unroll
  for (int ks = 0; ks < 2; ++ks)
#pragma unroll
    for (int c = 0; c < 4; ++c) {
      bf16x8 t, b;
#pragma unroll
      for (int jj = 0; jj < 8; ++jj) {
        int k = 32 * ks + 8 * g + jj;
        t[jj] = (__bf16)W1[(size_t)k * 64 + 16 * c + r16];
        b[jj] = (__bf16)W1[(size_t)(64 + k) * 64 + 16 * c + r16];
      }
      wt[ks][c] = t; wb[ks][c] = b;
    }
  float b1c[4];
#pragma unroll
  for (int c = 0; c < 4; ++c) b1c[c] = b1[16 * c + r16];

  const int nTiles = (N + 15) >> 4;
  for (int tile = wid; tile < nTiles; tile += nw) {
    const int a0 = tile * 16;
    int arow = a0 + r16; if (arow >= N) arow = N - 1;

    bf16x8 af[2];
#pragma unroll
    for (int ks = 0; ks < 2; ++ks) {
      const float* p = atom_fea + (size_t)arow * 64 + 32 * ks + 8 * g;
      f32x4 x0 = *(const f32x4*)p;
      f32x4 x1 = *(const f32x4*)(p + 4);
      bf16x8 a;
#pragma unroll
      for (int jj = 0; jj < 4; ++jj) { a[jj] = (__bf16)x0[jj]; a[4 + jj] = (__bf16)x1[jj]; }
      af[ks] = a;
    }

    f32x4 uacc[4], yacc[4];
#pragma unroll
    for (int c = 0; c < 4; ++c) { uacc[c] = (f32x4)0.0f; yacc[c] = (f32x4)0.0f; }
#pragma unroll
    for (int ks = 0; ks < 2; ++ks)
#pragma unroll
      for (int c = 0; c < 4; ++c) {
        uacc[c] = __builtin_amdgcn_mfma_f32_16x16x32_bf16(af[ks], wt[ks][c], uacc[c], 0, 0, 0);
        yacc[c] = __builtin_amdgcn_mfma_f32_16x16x32_bf16(af[ks], wb[ks][c], yacc[c], 0, 0, 0);
      }

#pragma unroll
    for (int c = 0; c < 4; ++c)
#pragma unroll
      for (int j = 0; j < 4; ++j) {
        int row = a0 + 4 * g + j;
        if (row < N) {
          Ub[(size_t)row * 64 + 16 * c + r16] = (__bf16)(uacc[c][j] + b1c[c]);
          Yb[(size_t)row * 64 + 16 * c + r16] = (__bf16)yacc[c][j];
        }
      }
  }
}

// ---------------------------------------------------------------------------
// Main fused kernel, v4: two ADJACENT segments per wave (shared row_start
// triple), full pair-head prefetch one grid-stride iteration ahead
// (row_start, U' rows, residuals), lean register state (U' kept bf16),
// interleaved shfl chains. pooled = (sum w_e H_e)@W2 + (sum w_e) b2.
// ---------------------------------------------------------------------------
__global__ __launch_bounds__(64, 4)
void fused_pool(const float* __restrict__ atom_w,
                const float* __restrict__ atom_fea,
                const int* __restrict__ nbr_idx,
                const float* __restrict__ W2,
                const float* __restrict__ b2,
                const float* __restrict__ Wg,
                const float* __restrict__ bg,
                const int* __restrict__ row_start,
                const __bf16* __restrict__ Ub,
                const __bf16* __restrict__ Yb,
                const __bf16* __restrict__ W2pack,
                float* __restrict__ out, int N) {
  const int lane = threadIdx.x & 63;
  const int r16 = lane & 15, g = lane >> 4;

  // wg2[k] = sum_d W2[k][d]*Wg[d]  (lane holds k = lane)
  float wgl = 0.f;
  {
    const float* w2row = W2 + (size_t)lane * 64;
#pragma unroll
    for (int d = 0; d < 64; ++d) wgl = fmaf(w2row[d], Wg[d], wgl);
  }
  // distribute wg2 into this lane's A-frag k-slots: k = 32ks + 8g + jj
  float wgsl[16];
#pragma unroll
  for (int ks = 0; ks < 2; ++ks)
#pragma unroll
    for (int jj = 0; jj < 8; ++jj)
      wgsl[ks * 8 + jj] = __shfl(wgl, 32 * ks + 8 * g + jj);

  // bgp = bg + sum_d b2[d]*Wg[d]
  float tb = b2[lane] * Wg[lane];
#pragma unroll
  for (int off = 1; off < 64; off <<= 1) tb += __shfl_xor(tb, off);
  const float bgp = bg[0] + tb;
  const float b2l = b2[lane];

  const int pstride = 2 * gridDim.x;
  int p = 2 * blockIdx.x;

  // ---- prefetch registers for the NEXT pair's head state ----
  int nrs0 = 0, nrs1 = 0, nrs2 = 0;
  bf16x8 nuA0 = {}, nuA1 = {}, nuB0 = {}, nuB1 = {};
  float nxrA = 0.f, nxrB = 0.f;

  auto issue_head = [&](int pp) {
    if (pp < N) {
      nrs0 = row_start[pp];
      nrs1 = row_start[pp + 1];
      const int i2 = (pp + 2 <= N) ? (pp + 2) : N;
      nrs2 = row_start[i2];
      const int pb = (pp + 1 < N) ? (pp + 1) : pp;
      nuA0 = *(const bf16x8*)(Ub + (size_t)pp * 64 + 8 * g);
      nuA1 = *(const bf16x8*)(Ub + (size_t)pp * 64 + 32 + 8 * g);
      nuB0 = *(const bf16x8*)(Ub + (size_t)pb * 64 + 8 * g);
      nuB1 = *(const bf16x8*)(Ub + (size_t)pb * 64 + 32 + 8 * g);
      nxrA = atom_fea[(size_t)pp * 64 + lane];
      nxrB = atom_fea[(size_t)pb * 64 + lane];
    }
  };

  issue_head(p);

  for (; p < N; p += pstride) {
    const int sA = p, sB = p + 1;
    const bool hasB = sB < N;

    const int startA = nrs0;
    const int endA = nrs1;                 // == startB (adjacent segments)
    const int startB = endA;
    const int endB = hasB ? nrs2 : endA;
    const bf16x8 uA0 = nuA0, uA1 = nuA1, uB0 = nuB0, uB1 = nuB1;
    const float xrA = nxrA, xrB = nxrB;

    issue_head(p + pstride);   // fire next pair's head loads now

    float zA[16], zB[16];
#pragma unroll
    for (int k = 0; k < 16; ++k) { zA[k] = 0.f; zB[k] = 0.f; }
    float wsA = 0.f, wsB = 0.f;

    const int nTA = (endA - startA + 15) >> 4;
    const int nTB = (endB - startB + 15) >> 4;
    const int nT = nTA > nTB ? nTA : nTB;

    for (int t = 0; t < nT; ++t) {
      const int baseA = startA + 16 * t;
      const int baseB = startB + 16 * t;
      const bool actA = baseA < endA;
      const bool actB = baseB < endB;

      // ---- issue both streams' loads up front ----
      int nbA = 0, nbB = 0; bool vA = false, vB = false;
      bf16x8 yA0 = {}, yA1 = {}, yB0 = {}, yB1 = {};
      float awA = 0.f, awB = 0.f;
      if (actA) {
        const int e = baseA + r16; vA = e < endA;
        nbA = vA ? nbr_idx[e] : 0;
        const __bf16* yr = Yb + ((size_t)nbA << 6);
        yA0 = *(const bf16x8*)(yr + 8 * g);
        yA1 = *(const bf16x8*)(yr + 32 + 8 * g);
        awA = atom_w[nbA];
      }
      if (actB) {
        const int e = baseB + r16; vB = e < endB;
        nbB = vB ? nbr_idx[e] : 0;
        const __bf16* yr = Yb + ((size_t)nbB << 6);
        yB0 = *(const bf16x8*)(yr + 8 * g);
        yB1 = *(const bf16x8*)(yr + 32 + 8 * g);
        awB = atom_w[nbB];
      }

      // ---- H + gate dot for both streams ----
      float hfA[16], hfB[16];
      float pA = 0.f, pB = 0.f;
      if (actA) {
#pragma unroll
        for (int jj = 0; jj < 8; ++jj) {
          float a = (float)uA0[jj] + (float)yA0[jj];
          float b = (float)uA1[jj] + (float)yA1[jj];
          hfA[jj] = fmaxf(a, 0.01f * a);
          hfA[8 + jj] = fmaxf(b, 0.01f * b);
        }
#pragma unroll
        for (int i = 0; i < 16; ++i) pA = fmaf(hfA[i], wgsl[i], pA);
      }
      if (actB) {
#pragma unroll
        for (int jj = 0; jj < 8; ++jj) {
          float a = (float)uB0[jj] + (float)yB0[jj];
          float b = (float)uB1[jj] + (float)yB1[jj];
          hfB[jj] = fmaxf(a, 0.01f * a);
          hfB[8 + jj] = fmaxf(b, 0.01f * b);
        }
#pragma unroll
        for (int i = 0; i < 16; ++i) pB = fmaf(hfB[i], wgsl[i], pB);
      }

      // interleaved reduce: B's chain hides A's ds_bpermute latency
      pA += __shfl_xor(pA, 16);
      pB += __shfl_xor(pB, 16);
      pA += __shfl_xor(pA, 32);
      pB += __shfl_xor(pB, 32);

      if (actA) {
        const float w = vA ? awA * __expf(pA + bgp) : 0.f;
        wsA += w;
#pragma unroll
        for (int k = 0; k < 16; ++k) zA[k] = fmaf(w, hfA[k], zA[k]);
      }
      if (actB) {
        const float w = vB ? awB * __expf(pB + bgp) : 0.f;
        wsB += w;
#pragma unroll
        for (int k = 0; k < 16; ++k) zB[k] = fmaf(w, hfB[k], zB[k]);
      }
    }

    // ---- finalize both segments; W2 frags loaded once ----
    bf16x8 zfA0, zfA1, zfB0, zfB1;
#pragma unroll
    for (int jj = 0; jj < 8; ++jj) {
      zfA0[jj] = (__bf16)zA[jj]; zfA1[jj] = (__bf16)zA[8 + jj];
      zfB0[jj] = (__bf16)zB[jj]; zfB1[jj] = (__bf16)zB[8 + jj];
    }

    f32x4 fA[4], fB[4];
#pragma unroll
    for (int c = 0; c < 4; ++c) { fA[c] = (f32x4)0.0f; fB[c] = (f32x4)0.0f; }
#pragma unroll
    for (int c = 0; c < 4; ++c) {
      const bf16x8 wf0 = *(const bf16x8*)(W2pack + ((size_t)(0 * 4 + c) * 64 + lane) * 8);
      const bf16x8 wf1 = *(const bf16x8*)(W2pack + ((size_t)(1 * 4 + c) * 64 + lane) * 8);
      fA[c] = __builtin_amdgcn_mfma_f32_16x16x32_bf16(zfA0, wf0, fA[c], 0, 0, 0);
      fA[c] = __builtin_amdgcn_mfma_f32_16x16x32_bf16(zfA1, wf1, fA[c], 0, 0, 0);
      fB[c] = __builtin_amdgcn_mfma_f32_16x16x32_bf16(zfB0, wf0, fB[c], 0, 0, 0);
      fB[c] = __builtin_amdgcn_mfma_f32_16x16x32_bf16(zfB1, wf1, fB[c], 0, 0, 0);
    }

    // reduce C rows (16 z-partial rows) -> pooled numerator per dim
    float avA[4], avB[4];
#pragma unroll
    for (int c = 0; c < 4; ++c) {
      float a = (fA[c][0] + fA[c][1]) + (fA[c][2] + fA[c][3]);
      float b = (fB[c][0] + fB[c][1]) + (fB[c][2] + fB[c][3]);
      a += __shfl_xor(a, 16); b += __shfl_xor(b, 16);
      a += __shfl_xor(a, 32); b += __shfl_xor(b, 32);
      avA[c] = a; avB[c] = b;
    }
    float ssA = wsA, ssB = wsB;
#pragma unroll
    for (int off = 1; off < 16; off <<= 1) {
      ssA += __shfl_xor(ssA, off);
      ssB += __shfl_xor(ssB, off);
    }

    float valA = avA[0];
    valA = (g == 1) ? avA[1] : valA;
    valA = (g == 2) ? avA[2] : valA;
    valA = (g == 3) ? avA[3] : valA;
    valA = fmaf(ssA, b2l, valA);
    out[(size_t)sA * 64 + lane] = valA / (ssA + 1e-13f) + xrA;

    if (hasB) {
      float valB = avB[0];
      valB = (g == 1) ? avB[1] : valB;
      valB = (g == 2) ? avB[2] : valB;
      valB = (g == 3) ? avB[3] : valB;
      valB = fmaf(ssB, b2l, valB);
      out[(size_t)sB * 64 + lane] = valB / (ssB + 1e-13f) + xrB;
    }
  }
}

extern "C" void kernel_launch(void* const* d_in, const int* in_sizes, int n_in,
                              void* d_out, int out_size, void* d_ws, size_t ws_size,
                              hipStream_t stream) {
  const float* atom_w   = (const float*)d_in[0];
  const float* atom_fea = (const float*)d_in[1];
  const int*   self_idx = (const int*)d_in[2];
  const int*   nbr_idx  = (const int*)d_in[3];
  const float* W1 = (const float*)d_in[4];
  const float* b1 = (const float*)d_in[5];
  const float* W2 = (const float*)d_in[6];
  const float* b2 = (const float*)d_in[7];
  const float* Wg = (const float*)d_in[8];
  const float* bg = (const float*)d_in[9];
  float* out = (float*)d_out;

  const int N = in_sizes[0];   // atom_weights is (N,1)
  const int M = in_sizes[2];   // self_fea_idx is (M,)

  char* ws = (char*)d_ws;
  int* row_start = (int*)ws;
  size_t off = ((size_t)(N + 1) * sizeof(int) + 255) & ~(size_t)255;
  __bf16* W2pack = (__bf16*)(ws + off);
  __bf16* Ub = W2pack + 8 * 64 * 8;          // 8KB pack region
  __bf16* Yb = Ub + (size_t)N * 64;

  hipLaunchKernelGGL(build_row_start, dim3((M + 255) / 256), dim3(256), 0,
                     stream, self_idx, row_start, M, N);
  hipLaunchKernelGGL(precompute_uy, dim3(512), dim3(256), 0, stream,
                     atom_fea, W1, b1, W2, Ub, Yb, W2pack, N);
  hipLaunchKernelGGL(fused_pool, dim3(8192), dim3(64), 0, stream,
                     atom_w, atom_fea, nbr_idx, W2, b2, Wg, bg,
                     row_start, Ub, Yb, W2pack, out, N);
}

// Round 8
// 148.398 us; speedup vs baseline: 2.4872x; 2.4872x over previous
//
#include <hip/hip_runtime.h>
#include <math.h>

typedef float f32x4 __attribute__((ext_vector_type(4)));
typedef __bf16 bf16x8 __attribute__((ext_vector_type(8)));

// ---------------------------------------------------------------------------
// CSR row offsets from sorted self_fea_idx. row_start[N] = M.
// ---------------------------------------------------------------------------
__global__ void build_row_start(const int* __restrict__ self_idx,
                                int* __restrict__ row_start, int M, int N) {
  int i = blockIdx.x * blockDim.x + threadIdx.x;
  if (i >= M) return;
  int cur = self_idx[i];
  int prev = (i == 0) ? -1 : self_idx[i - 1];
  for (int j = prev + 1; j <= cur; ++j) row_start[j] = i;
  if (i == M - 1) {
    for (int j = cur + 1; j <= N; ++j) row_start[j] = M;
  }
}

// ---------------------------------------------------------------------------
// Phase A: per-atom precompute of layer-1 halves (bf16 in ws) and a
// B-frag-packed copy of W2.
//   U'[a][d] = sum_k X[a][k]*W1[k][d] + b1[d]
//   Y [a][d] = sum_k X[a][k]*W1[64+k][d]
//   W2pack[(ks*4+c)*64 + lane][0..7] = W2[32ks+8g+j][16c+r16], lane=16g+r16
// ---------------------------------------------------------------------------
__global__ __launch_bounds__(256, 2)
void precompute_uy(const float* __restrict__ atom_fea,
                   const float* __restrict__ W1,
                   const float* __restrict__ b1,
                   const float* __restrict__ W2,
                   __bf16* __restrict__ Ub, __bf16* __restrict__ Yb,
                   __bf16* __restrict__ W2pack, int N) {
  const int lane = threadIdx.x & 63;
  const int r16 = lane & 15, g = lane >> 4;
  const int wid = (blockIdx.x * blockDim.x + threadIdx.x) >> 6;
  const int nw = (gridDim.x * blockDim.x) >> 6;

  if (wid == 0) {  // pack W2 into B-frag order (8 KB, once)
#pragma unroll
    for (int ks = 0; ks < 2; ++ks)
#pragma unroll
      for (int c = 0; c < 4; ++c) {
        bf16x8 t;
#pragma unroll
        for (int jj = 0; jj < 8; ++jj)
          t[jj] = (__bf16)W2[(size_t)(32 * ks + 8 * g + jj) * 64 + 16 * c + r16];
        *(bf16x8*)(W2pack + ((size_t)(ks * 4 + c) * 64 + lane) * 8) = t;
      }
  }

  bf16x8 wt[2][4], wb[2][4];
#pragma unroll
  for (int ks = 0; ks < 2; ++ks)
#pragma unroll
    for (int c = 0; c < 4; ++c) {
      bf16x8 t, b;
#pragma unroll
      for (int jj = 0; jj < 8; ++jj) {
        int k = 32 * ks + 8 * g + jj;
        t[jj] = (__bf16)W1[(size_t)k * 64 + 16 * c + r16];
        b[jj] = (__bf16)W1[(size_t)(64 + k) * 64 + 16 * c + r16];
      }
      wt[ks][c] = t; wb[ks][c] = b;
    }
  float b1c[4];
#pragma unroll
  for (int c = 0; c < 4; ++c) b1c[c] = b1[16 * c + r16];

  const int nTiles = (N + 15) >> 4;
  for (int tile = wid; tile < nTiles; tile += nw) {
    const int a0 = tile * 16;
    int arow = a0 + r16; if (arow >= N) arow = N - 1;

    bf16x8 af[2];
#pragma unroll
    for (int ks = 0; ks < 2; ++ks) {
      const float* p = atom_fea + (size_t)arow * 64 + 32 * ks + 8 * g;
      f32x4 x0 = *(const f32x4*)p;
      f32x4 x1 = *(const f32x4*)(p + 4);
      bf16x8 a;
#pragma unroll
      for (int jj = 0; jj < 4; ++jj) { a[jj] = (__bf16)x0[jj]; a[4 + jj] = (__bf16)x1[jj]; }
      af[ks] = a;
    }

    f32x4 uacc[4], yacc[4];
#pragma unroll
    for (int c = 0; c < 4; ++c) { uacc[c] = (f32x4)0.0f; yacc[c] = (f32x4)0.0f; }
#pragma unroll
    for (int ks = 0; ks < 2; ++ks)
#pragma unroll
      for (int c = 0; c < 4; ++c) {
        uacc[c] = __builtin_amdgcn_mfma_f32_16x16x32_bf16(af[ks], wt[ks][c], uacc[c], 0, 0, 0);
        yacc[c] = __builtin_amdgcn_mfma_f32_16x16x32_bf16(af[ks], wb[ks][c], yacc[c], 0, 0, 0);
      }

#pragma unroll
    for (int c = 0; c < 4; ++c)
#pragma unroll
      for (int j = 0; j < 4; ++j) {
        int row = a0 + 4 * g + j;
        if (row < N) {
          Ub[(size_t)row * 64 + 16 * c + r16] = (__bf16)(uacc[c][j] + b1c[c]);
          Yb[(size_t)row * 64 + 16 * c + r16] = (__bf16)yacc[c][j];
        }
      }
  }
}

// ---------------------------------------------------------------------------
// Main fused kernel (R5 structure, launch-shape experiment).
// One wave per segment; algebraic form:
//   pooled = (sum_e w_e H_e) @ W2 + (sum_e w_e) b2
//   w_e = atom_w[nbr_e]*exp(H_e.wg2 + bgp),  wg2 = W2@Wg, bgp = bg + b2.Wg
// Per 16-edge tile: gather Y rows, H in f32 regs, gate dot + 2 shfl_xor,
// one exp, z-FMA. Per segment: z -> bf16 A-frag, 8 MFMA vs packed W2 frags.
// Rotating prefetch of next segment's head (row_start + U' row).
// 256-thread blocks = 4 independent waves; grid 3x oversubscribed so the
// scheduler can backfill (tests the 39%-occupancy residency cap).
// ---------------------------------------------------------------------------
__global__ __launch_bounds__(256, 4)
void fused_pool(const float* __restrict__ atom_w,
                const float* __restrict__ atom_fea,
                const int* __restrict__ nbr_idx,
                const float* __restrict__ W2,
                const float* __restrict__ b2,
                const float* __restrict__ Wg,
                const float* __restrict__ bg,
                const int* __restrict__ row_start,
                const __bf16* __restrict__ Ub,
                const __bf16* __restrict__ Yb,
                const __bf16* __restrict__ W2pack,
                float* __restrict__ out, int N) {
  const int lane = threadIdx.x & 63;
  const int r16 = lane & 15, g = lane >> 4;
  const int wid = (blockIdx.x * blockDim.x + threadIdx.x) >> 6;
  const int nw = (gridDim.x * blockDim.x) >> 6;

  // wg2[k] = sum_d W2[k][d]*Wg[d]  (lane holds k = lane)
  float wgl = 0.f;
  {
    const float* w2row = W2 + (size_t)lane * 64;
#pragma unroll
    for (int d = 0; d < 64; ++d) wgl = fmaf(w2row[d], Wg[d], wgl);
  }
  // distribute wg2 into this lane's A-frag k-slots: k = 32ks + 8g + jj
  float wgsl[16];
#pragma unroll
  for (int ks = 0; ks < 2; ++ks)
#pragma unroll
    for (int jj = 0; jj < 8; ++jj)
      wgsl[ks * 8 + jj] = __shfl(wgl, 32 * ks + 8 * g + jj);

  // bgp = bg + sum_d b2[d]*Wg[d]
  float tb = b2[lane] * Wg[lane];
#pragma unroll
  for (int off = 1; off < 64; off <<= 1) tb += __shfl_xor(tb, off);
  const float bgp = bg[0] + tb;
  const float b2l = b2[lane];

  // rotating prefetch of next segment's CSR range + U' row
  int s = wid;
  int nStart = 0, nEnd = 0;
  bf16x8 nu0 = {}, nu1 = {};
  if (s < N) {
    nStart = row_start[s];
    nEnd = row_start[s + 1];
    nu0 = *(const bf16x8*)(Ub + (size_t)s * 64 + 8 * g);
    nu1 = *(const bf16x8*)(Ub + (size_t)s * 64 + 32 + 8 * g);
  }

  for (; s < N; s += nw) {
    const int start = nStart, end = nEnd;
    const bf16x8 u0 = nu0, u1 = nu1;
    const float xr = atom_fea[(size_t)s * 64 + lane];  // residual

    const int s2 = s + nw;
    if (s2 < N) {
      nStart = row_start[s2];
      nEnd = row_start[s2 + 1];
      nu0 = *(const bf16x8*)(Ub + (size_t)s2 * 64 + 8 * g);
      nu1 = *(const bf16x8*)(Ub + (size_t)s2 * 64 + 32 + 8 * g);
    }

    float uf[16];
#pragma unroll
    for (int jj = 0; jj < 8; ++jj) {
      uf[jj] = (float)u0[jj];
      uf[8 + jj] = (float)u1[jj];
    }

    float zacc[16];
#pragma unroll
    for (int k = 0; k < 16; ++k) zacc[k] = 0.f;
    float wsum = 0.f;

    for (int base = start; base < end; base += 16) {
      const int er = base + r16;
      const bool valid = er < end;
      const int nb = valid ? nbr_idx[er] : 0;
      const float aw = atom_w[nb];
      const __bf16* yrow = Yb + ((size_t)nb << 6);
      const bf16x8 y0 = *(const bf16x8*)(yrow + 8 * g);
      const bf16x8 y1 = *(const bf16x8*)(yrow + 32 + 8 * g);

      // H in f32 registers (A-frag slot order)
      float hf[16];
#pragma unroll
      for (int jj = 0; jj < 8; ++jj) {
        float a = uf[jj] + (float)y0[jj];
        float b = uf[8 + jj] + (float)y1[jj];
        hf[jj] = fmaxf(a, 0.01f * a);          // leaky_relu slope 0.01
        hf[8 + jj] = fmaxf(b, 0.01f * b);
      }

      // gate_e = H_e . wg2 (+bgp) : per-lane partial + reduce across g-groups
      float p0 = 0.f, p1 = 0.f;
#pragma unroll
      for (int i = 0; i < 8; ++i) {
        p0 = fmaf(hf[i], wgsl[i], p0);
        p1 = fmaf(hf[8 + i], wgsl[8 + i], p1);
      }
      float p = p0 + p1;
      p += __shfl_xor(p, 16);
      p += __shfl_xor(p, 32);

      const float w = valid ? aw * __expf(p + bgp) : 0.f;
      wsum += w;
#pragma unroll
      for (int k = 0; k < 16; ++k) zacc[k] = fmaf(w, hf[k], zacc[k]);
    }

    // ---- segment finalize: pooled = z @ W2 + wsum*b2, then /ssum + x ----
    bf16x8 zf0, zf1;
#pragma unroll
    for (int jj = 0; jj < 8; ++jj) {
      zf0[jj] = (__bf16)zacc[jj];
      zf1[jj] = (__bf16)zacc[8 + jj];
    }

    f32x4 facc[4];
#pragma unroll
    for (int c = 0; c < 4; ++c) facc[c] = (f32x4)0.0f;
#pragma unroll
    for (int c = 0; c < 4; ++c) {
      const bf16x8 wf0 = *(const bf16x8*)(W2pack + ((size_t)(0 * 4 + c) * 64 + lane) * 8);
      const bf16x8 wf1 = *(const bf16x8*)(W2pack + ((size_t)(1 * 4 + c) * 64 + lane) * 8);
      facc[c] = __builtin_amdgcn_mfma_f32_16x16x32_bf16(zf0, wf0, facc[c], 0, 0, 0);
      facc[c] = __builtin_amdgcn_mfma_f32_16x16x32_bf16(zf1, wf1, facc[c], 0, 0, 0);
    }

    // sum over the 16 C rows (Z partial rows): in-lane + cross-g shfl
    float accv[4];
#pragma unroll
    for (int c = 0; c < 4; ++c) {
      float a = (facc[c][0] + facc[c][1]) + (facc[c][2] + facc[c][3]);
      a += __shfl_xor(a, 16);
      a += __shfl_xor(a, 32);
      accv[c] = a;   // = pooled_num[16c + r16] (pre-b2)
    }

    // ssum = sum over r16 groups of per-lane wsum
    float ssum = wsum;
    ssum += __shfl_xor(ssum, 1);
    ssum += __shfl_xor(ssum, 2);
    ssum += __shfl_xor(ssum, 4);
    ssum += __shfl_xor(ssum, 8);

    // lane's output dim d = lane = 16g + r16 -> chunk c = g
    float val = accv[0];
    val = (g == 1) ? accv[1] : val;
    val = (g == 2) ? accv[2] : val;
    val = (g == 3) ? accv[3] : val;
    val = fmaf(ssum, b2l, val);

    out[(size_t)s * 64 + lane] = val / (ssum + 1e-13f) + xr;
  }
}

extern "C" void kernel_launch(void* const* d_in, const int* in_sizes, int n_in,
                              void* d_out, int out_size, void* d_ws, size_t ws_size,
                              hipStream_t stream) {
  const float* atom_w   = (const float*)d_in[0];
  const float* atom_fea = (const float*)d_in[1];
  const int*   self_idx = (const int*)d_in[2];
  const int*   nbr_idx  = (const int*)d_in[3];
  const float* W1 = (const float*)d_in[4];
  const float* b1 = (const float*)d_in[5];
  const float* W2 = (const float*)d_in[6];
  const float* b2 = (const float*)d_in[7];
  const float* Wg = (const float*)d_in[8];
  const float* bg = (const float*)d_in[9];
  float* out = (float*)d_out;

  const int N = in_sizes[0];   // atom_weights is (N,1)
  const int M = in_sizes[2];   // self_fea_idx is (M,)

  char* ws = (char*)d_ws;
  int* row_start = (int*)ws;
  size_t off = ((size_t)(N + 1) * sizeof(int) + 255) & ~(size_t)255;
  __bf16* W2pack = (__bf16*)(ws + off);
  __bf16* Ub = W2pack + 8 * 64 * 8;          // 8KB pack region
  __bf16* Yb = Ub + (size_t)N * 64;

  hipLaunchKernelGGL(build_row_start, dim3((M + 255) / 256), dim3(256), 0,
                     stream, self_idx, row_start, M, N);
  hipLaunchKernelGGL(precompute_uy, dim3(512), dim3(256), 0, stream,
                     atom_fea, W1, b1, W2, Ub, Yb, W2pack, N);
  hipLaunchKernelGGL(fused_pool, dim3(6144), dim3(256), 0, stream,
                     atom_w, atom_fea, nbr_idx, W2, b2, Wg, bg,
                     row_start, Ub, Yb, W2pack, out, N);
}

// Round 9
// 132.189 us; speedup vs baseline: 2.7922x; 1.1226x over previous
//
#include <hip/hip_runtime.h>
#include <math.h>

typedef float f32x4 __attribute__((ext_vector_type(4)));
typedef float f32x2 __attribute__((ext_vector_type(2)));
typedef __bf16 bf16x8 __attribute__((ext_vector_type(8)));
typedef unsigned int u32;
typedef u32 u32x4 __attribute__((ext_vector_type(4)));

// bf16 pair (packed in one u32) -> f32x2, 2 VALU ops, no v_cvt.
__device__ __forceinline__ f32x2 bfpair(u32 u) {
  f32x2 r;
  r[0] = __builtin_bit_cast(float, u << 16);
  r[1] = __builtin_bit_cast(float, u & 0xffff0000u);
  return r;
}

// ---------------------------------------------------------------------------
// CSR row offsets from sorted self_fea_idx. row_start[N] = M.
// ---------------------------------------------------------------------------
__global__ void build_row_start(const int* __restrict__ self_idx,
                                int* __restrict__ row_start, int M, int N) {
  int i = blockIdx.x * blockDim.x + threadIdx.x;
  if (i >= M) return;
  int cur = self_idx[i];
  int prev = (i == 0) ? -1 : self_idx[i - 1];
  for (int j = prev + 1; j <= cur; ++j) row_start[j] = i;
  if (i == M - 1) {
    for (int j = cur + 1; j <= N; ++j) row_start[j] = M;
  }
}

// ---------------------------------------------------------------------------
// Phase A: per-atom precompute of layer-1 halves (bf16 in ws) and a
// B-frag-packed copy of W2.  (unchanged from R5)
// ---------------------------------------------------------------------------
__global__ __launch_bounds__(256, 2)
void precompute_uy(const float* __restrict__ atom_fea,
                   const float* __restrict__ W1,
                   const float* __restrict__ b1,
                   const float* __restrict__ W2,
                   __bf16* __restrict__ Ub, __bf16* __restrict__ Yb,
                   __bf16* __restrict__ W2pack, int N) {
  const int lane = threadIdx.x & 63;
  const int r16 = lane & 15, g = lane >> 4;
  const int wid = (blockIdx.x * blockDim.x + threadIdx.x) >> 6;
  const int nw = (gridDim.x * blockDim.x) >> 6;

  if (wid == 0) {  // pack W2 into B-frag order (8 KB, once)
#pragma unroll
    for (int ks = 0; ks < 2; ++ks)
#pragma unroll
      for (int c = 0; c < 4; ++c) {
        bf16x8 t;
#pragma unroll
        for (int jj = 0; jj < 8; ++jj)
          t[jj] = (__bf16)W2[(size_t)(32 * ks + 8 * g + jj) * 64 + 16 * c + r16];
        *(bf16x8*)(W2pack + ((size_t)(ks * 4 + c) * 64 + lane) * 8) = t;
      }
  }

  bf16x8 wt[2][4], wb[2][4];
#pragma unroll
  for (int ks = 0; ks < 2; ++ks)
#pragma unroll
    for (int c = 0; c < 4; ++c) {
      bf16x8 t, b;
#pragma unroll
      for (int jj = 0; jj < 8; ++jj) {
        int k = 32 * ks + 8 * g + jj;
        t[jj] = (__bf16)W1[(size_t)k * 64 + 16 * c + r16];
        b[jj] = (__bf16)W1[(size_t)(64 + k) * 64 + 16 * c + r16];
      }
      wt[ks][c] = t; wb[ks][c] = b;
    }
  float b1c[4];
#pragma unroll
  for (int c = 0; c < 4; ++c) b1c[c] = b1[16 * c + r16];

  const int nTiles = (N + 15) >> 4;
  for (int tile = wid; tile < nTiles; tile += nw) {
    const int a0 = tile * 16;
    int arow = a0 + r16; if (arow >= N) arow = N - 1;

    bf16x8 af[2];
#pragma unroll
    for (int ks = 0; ks < 2; ++ks) {
      const float* p = atom_fea + (size_t)arow * 64 + 32 * ks + 8 * g;
      f32x4 x0 = *(const f32x4*)p;
      f32x4 x1 = *(const f32x4*)(p + 4);
      bf16x8 a;
#pragma unroll
      for (int jj = 0; jj < 4; ++jj) { a[jj] = (__bf16)x0[jj]; a[4 + jj] = (__bf16)x1[jj]; }
      af[ks] = a;
    }

    f32x4 uacc[4], yacc[4];
#pragma unroll
    for (int c = 0; c < 4; ++c) { uacc[c] = (f32x4)0.0f; yacc[c] = (f32x4)0.0f; }
#pragma unroll
    for (int ks = 0; ks < 2; ++ks)
#pragma unroll
      for (int c = 0; c < 4; ++c) {
        uacc[c] = __builtin_amdgcn_mfma_f32_16x16x32_bf16(af[ks], wt[ks][c], uacc[c], 0, 0, 0);
        yacc[c] = __builtin_amdgcn_mfma_f32_16x16x32_bf16(af[ks], wb[ks][c], yacc[c], 0, 0, 0);
      }

#pragma unroll
    for (int c = 0; c < 4; ++c)
#pragma unroll
      for (int j = 0; j < 4; ++j) {
        int row = a0 + 4 * g + j;
        if (row < N) {
          Ub[(size_t)row * 64 + 16 * c + r16] = (__bf16)(uacc[c][j] + b1c[c]);
          Yb[(size_t)row * 64 + 16 * c + r16] = (__bf16)yacc[c][j];
        }
      }
  }
}

// ---------------------------------------------------------------------------
// Main fused kernel v5: R5 structure + packed-f32 math + 2-deep pipeline.
//   pooled = (sum_e w_e H_e) @ W2 + (sum_e w_e) b2
//   w_e = atom_w[nbr_e]*exp(H_e.wg2 + bgp),  wg2 = W2@Wg, bgp = bg + b2.Wg
// Pipeline per wave (stride nw over segments):
//   at segment s: issue row_start(s+2nw); issue nbr(first tile of s+nw);
//   compute tile0 (Y prefetched a full segment ago); issue Y(first tile s+nw);
//   remaining tiles with rolling nbr-index prefetch; finalize via 8 MFMA;
//   rotate and issue U'/res(s+2nw).
// ---------------------------------------------------------------------------
__global__ __launch_bounds__(64, 4)
void fused_pool(const float* __restrict__ atom_w,
                const float* __restrict__ atom_fea,
                const int* __restrict__ nbr_idx,
                const float* __restrict__ W2,
                const float* __restrict__ b2,
                const float* __restrict__ Wg,
                const float* __restrict__ bg,
                const int* __restrict__ row_start,
                const __bf16* __restrict__ Ub,
                const __bf16* __restrict__ Yb,
                const __bf16* __restrict__ W2pack,
                float* __restrict__ out, int N) {
  const int lane = threadIdx.x & 63;
  const int r16 = lane & 15, g = lane >> 4;
  const int wid = blockIdx.x;
  const int nw = gridDim.x;

  // wg2[k] = sum_d W2[k][d]*Wg[d]  (lane holds k = lane)
  float wgl = 0.f;
  {
    const float* w2row = W2 + (size_t)lane * 64;
#pragma unroll
    for (int d = 0; d < 64; ++d) wgl = fmaf(w2row[d], Wg[d], wgl);
  }
  // distribute wg2 into this lane's A-frag k-slots (k = 32ks + 8g + jj),
  // packed into f32x2 pairs.
  f32x2 wg2p[8];
#pragma unroll
  for (int pI = 0; pI < 8; ++pI) {
    const int ks = pI >> 2, jj = (pI & 3) * 2;
    f32x2 t;
    t[0] = __shfl(wgl, 32 * ks + 8 * g + jj);
    t[1] = __shfl(wgl, 32 * ks + 8 * g + jj + 1);
    wg2p[pI] = t;
  }

  // bgp = bg + sum_d b2[d]*Wg[d]
  float tb = b2[lane] * Wg[lane];
#pragma unroll
  for (int off = 1; off < 64; off <<= 1) tb += __shfl_xor(tb, off);
  const float bgp = bg[0] + tb;
  const float b2l = b2[lane];

  // ---- pipeline registers ----
  int s = wid;
  if (s >= N) return;

  int curS, curE;               // bounds of s
  int nxtS = 0, nxtE = 0;       // bounds of s+nw (arrived)
  int nnS = 0, nnE = 0;         // bounds of s+2nw (in flight)
  u32x4 cu0, cu1; float cxr;    // U' + residual of s
  u32x4 nu0 = {}, nu1 = {}; float nxr = 0.f;   // of s+nw
  u32x4 fy0, fy1; float faw; bool fv;          // first tile Y of s (arrived)
  u32x4 py0 = {}, py1 = {}; float paw = 0.f; bool pv = false; int pnb = 0;

  // ---- prologue (one-time exposed latency) ----
  curS = row_start[s]; curE = row_start[s + 1];
  cu0 = *(const u32x4*)(Ub + (size_t)s * 64 + 8 * g);
  cu1 = *(const u32x4*)(Ub + (size_t)s * 64 + 32 + 8 * g);
  cxr = atom_fea[(size_t)s * 64 + lane];
  {
    const int e = curS + r16; fv = e < curE;
    const int nb = fv ? nbr_idx[e] : 0;
    fy0 = *(const u32x4*)(Yb + ((size_t)nb << 6) + 8 * g);
    fy1 = *(const u32x4*)(Yb + ((size_t)nb << 6) + 32 + 8 * g);
    faw = atom_w[nb];
  }
  if (s + nw < N) {
    nxtS = row_start[s + nw]; nxtE = row_start[s + nw + 1];
    nu0 = *(const u32x4*)(Ub + (size_t)(s + nw) * 64 + 8 * g);
    nu1 = *(const u32x4*)(Ub + (size_t)(s + nw) * 64 + 32 + 8 * g);
    nxr = atom_fea[(size_t)(s + nw) * 64 + lane];
  }

  for (; s < N; s += nw) {
    const int start = curS, end = curE;
    const int s1 = s + nw, s2 = s + 2 * nw;

    // (1) issue row_start for s+2nw (uniform)
    if (s2 < N) { nnS = row_start[s2]; nnE = row_start[s2 + 1]; }

    // (2) issue first-tile nbr index for s+nw
    if (s1 < N) {
      const int e = nxtS + r16; pv = e < nxtE;
      pnb = pv ? nbr_idx[e] : 0;
    }
    // rolling nbr prefetch for this segment's tile 1
    int nb1 = (start + 16 + r16 < end) ? nbr_idx[start + 16 + r16] : 0;

    // unpack U' to f32x2 pairs
    f32x2 uf2[8];
#pragma unroll
    for (int pI = 0; pI < 4; ++pI) {
      uf2[pI] = bfpair(cu0[pI]);
      uf2[4 + pI] = bfpair(cu1[pI]);
    }

    f32x2 z2[8];
#pragma unroll
    for (int k = 0; k < 8; ++k) z2[k] = (f32x2)0.0f;
    float wsum = 0.f;

    // ---- tile 0 (Y prefetched one full segment ago) ----
    {
      f32x2 h2[8];
      f32x2 d2 = (f32x2)0.0f;
#pragma unroll
      for (int pI = 0; pI < 8; ++pI) {
        const u32 yw = (pI < 4) ? fy0[pI] : fy1[pI - 4];
        f32x2 a = uf2[pI] + bfpair(yw);
        f32x2 t = a * 0.01f;
        f32x2 h; h[0] = fmaxf(a[0], t[0]); h[1] = fmaxf(a[1], t[1]);
        h2[pI] = h;
        d2 += h * wg2p[pI];
      }
      float p = d2[0] + d2[1];
      p += __shfl_xor(p, 16);
      p += __shfl_xor(p, 32);
      const float w = fv ? faw * __expf(p + bgp) : 0.f;
      wsum += w;
      const f32x2 w2 = {w, w};
#pragma unroll
      for (int k = 0; k < 8; ++k) z2[k] += w2 * h2[k];
    }

    // (3) issue first-tile Y for s+nw (pnb arrived during tile 0)
    if (s1 < N) {
      py0 = *(const u32x4*)(Yb + ((size_t)pnb << 6) + 8 * g);
      py1 = *(const u32x4*)(Yb + ((size_t)pnb << 6) + 32 + 8 * g);
      paw = atom_w[pnb];
    }

    // ---- remaining tiles ----
    for (int base = start + 16; base < end; base += 16) {
      const bool v = base + r16 < end;
      const int nb = nb1;
      nb1 = (base + 16 + r16 < end) ? nbr_idx[base + 16 + r16] : 0;
      const u32x4 y0 = *(const u32x4*)(Yb + ((size_t)nb << 6) + 8 * g);
      const u32x4 y1 = *(const u32x4*)(Yb + ((size_t)nb << 6) + 32 + 8 * g);
      const float aw = atom_w[nb];

      f32x2 h2[8];
      f32x2 d2 = (f32x2)0.0f;
#pragma unroll
      for (int pI = 0; pI < 8; ++pI) {
        const u32 yw = (pI < 4) ? y0[pI] : y1[pI - 4];
        f32x2 a = uf2[pI] + bfpair(yw);
        f32x2 t = a * 0.01f;
        f32x2 h; h[0] = fmaxf(a[0], t[0]); h[1] = fmaxf(a[1], t[1]);
        h2[pI] = h;
        d2 += h * wg2p[pI];
      }
      float p = d2[0] + d2[1];
      p += __shfl_xor(p, 16);
      p += __shfl_xor(p, 32);
      const float w = v ? aw * __expf(p + bgp) : 0.f;
      wsum += w;
      const f32x2 w2 = {w, w};
#pragma unroll
      for (int k = 0; k < 8; ++k) z2[k] += w2 * h2[k];
    }

    // ---- finalize: pooled = z @ W2 + wsum*b2, then /ssum + residual ----
    bf16x8 zf0, zf1;
#pragma unroll
    for (int pI = 0; pI < 4; ++pI) {
      zf0[2 * pI] = (__bf16)z2[pI][0];
      zf0[2 * pI + 1] = (__bf16)z2[pI][1];
      zf1[2 * pI] = (__bf16)z2[4 + pI][0];
      zf1[2 * pI + 1] = (__bf16)z2[4 + pI][1];
    }

    f32x4 facc[4];
#pragma unroll
    for (int c = 0; c < 4; ++c) facc[c] = (f32x4)0.0f;
#pragma unroll
    for (int c = 0; c < 4; ++c) {
      const bf16x8 wf0 = *(const bf16x8*)(W2pack + ((size_t)(0 * 4 + c) * 64 + lane) * 8);
      const bf16x8 wf1 = *(const bf16x8*)(W2pack + ((size_t)(1 * 4 + c) * 64 + lane) * 8);
      facc[c] = __builtin_amdgcn_mfma_f32_16x16x32_bf16(zf0, wf0, facc[c], 0, 0, 0);
      facc[c] = __builtin_amdgcn_mfma_f32_16x16x32_bf16(zf1, wf1, facc[c], 0, 0, 0);
    }

    float accv[4];
#pragma unroll
    for (int c = 0; c < 4; ++c) {
      float a = (facc[c][0] + facc[c][1]) + (facc[c][2] + facc[c][3]);
      a += __shfl_xor(a, 16);
      a += __shfl_xor(a, 32);
      accv[c] = a;
    }
    float ssum = wsum;
    ssum += __shfl_xor(ssum, 1);
    ssum += __shfl_xor(ssum, 2);
    ssum += __shfl_xor(ssum, 4);
    ssum += __shfl_xor(ssum, 8);

    float val = accv[0];
    val = (g == 1) ? accv[1] : val;
    val = (g == 2) ? accv[2] : val;
    val = (g == 3) ? accv[3] : val;
    val = fmaf(ssum, b2l, val);

    out[(size_t)s * 64 + lane] = val / (ssum + 1e-13f) + cxr;

    // ---- rotate pipeline; issue U'/residual for s+2nw ----
    curS = nxtS; curE = nxtE;
    cu0 = nu0; cu1 = nu1; cxr = nxr;
    nxtS = nnS; nxtE = nnE;
    if (s2 < N) {
      nu0 = *(const u32x4*)(Ub + (size_t)s2 * 64 + 8 * g);
      nu1 = *(const u32x4*)(Ub + (size_t)s2 * 64 + 32 + 8 * g);
      nxr = atom_fea[(size_t)s2 * 64 + lane];
    }
    fy0 = py0; fy1 = py1; faw = paw; fv = pv;
  }
}

extern "C" void kernel_launch(void* const* d_in, const int* in_sizes, int n_in,
                              void* d_out, int out_size, void* d_ws, size_t ws_size,
                              hipStream_t stream) {
  const float* atom_w   = (const float*)d_in[0];
  const float* atom_fea = (const float*)d_in[1];
  const int*   self_idx = (const int*)d_in[2];
  const int*   nbr_idx  = (const int*)d_in[3];
  const float* W1 = (const float*)d_in[4];
  const float* b1 = (const float*)d_in[5];
  const float* W2 = (const float*)d_in[6];
  const float* b2 = (const float*)d_in[7];
  const float* Wg = (const float*)d_in[8];
  const float* bg = (const float*)d_in[9];
  float* out = (float*)d_out;

  const int N = in_sizes[0];   // atom_weights is (N,1)
  const int M = in_sizes[2];   // self_fea_idx is (M,)

  char* ws = (char*)d_ws;
  int* row_start = (int*)ws;
  size_t off = ((size_t)(N + 1) * sizeof(int) + 255) & ~(size_t)255;
  __bf16* W2pack = (__bf16*)(ws + off);
  __bf16* Ub = W2pack + 8 * 64 * 8;          // 8KB pack region
  __bf16* Yb = Ub + (size_t)N * 64;

  hipLaunchKernelGGL(build_row_start, dim3((M + 255) / 256), dim3(256), 0,
                     stream, self_idx, row_start, M, N);
  hipLaunchKernelGGL(precompute_uy, dim3(512), dim3(256), 0, stream,
                     atom_fea, W1, b1, W2, Ub, Yb, W2pack, N);
  hipLaunchKernelGGL(fused_pool, dim3(8192), dim3(64), 0, stream,
                     atom_w, atom_fea, nbr_idx, W2, b2, Wg, bg,
                     row_start, Ub, Yb, W2pack, out, N);
}

// Round 10
// 112.703 us; speedup vs baseline: 3.2750x; 1.1729x over previous
//
#include <hip/hip_runtime.h>
#include <math.h>

typedef float f32x4 __attribute__((ext_vector_type(4)));
typedef float f32x2 __attribute__((ext_vector_type(2)));
typedef __bf16 bf16x8 __attribute__((ext_vector_type(8)));
typedef unsigned int u32;
typedef u32 u32x4 __attribute__((ext_vector_type(4)));

// bf16 pair (packed in one u32) -> f32x2, 2 VALU ops, no v_cvt.
__device__ __forceinline__ f32x2 bfpair(u32 u) {
  f32x2 r;
  r[0] = __builtin_bit_cast(float, u << 16);
  r[1] = __builtin_bit_cast(float, u & 0xffff0000u);
  return r;
}

// ---------------------------------------------------------------------------
// CSR row offsets from sorted self_fea_idx. row_start[N] = M.
// ---------------------------------------------------------------------------
__global__ void build_row_start(const int* __restrict__ self_idx,
                                int* __restrict__ row_start, int M, int N) {
  int i = blockIdx.x * blockDim.x + threadIdx.x;
  if (i >= M) return;
  int cur = self_idx[i];
  int prev = (i == 0) ? -1 : self_idx[i - 1];
  for (int j = prev + 1; j <= cur; ++j) row_start[j] = i;
  if (i == M - 1) {
    for (int j = cur + 1; j <= N; ++j) row_start[j] = M;
  }
}

// ---------------------------------------------------------------------------
// Phase A: per-atom precompute of layer-1 halves (bf16 in ws) and a
// B-frag-packed copy of W2.  (unchanged)
// ---------------------------------------------------------------------------
__global__ __launch_bounds__(256, 2)
void precompute_uy(const float* __restrict__ atom_fea,
                   const float* __restrict__ W1,
                   const float* __restrict__ b1,
                   const float* __restrict__ W2,
                   __bf16* __restrict__ Ub, __bf16* __restrict__ Yb,
                   __bf16* __restrict__ W2pack, int N) {
  const int lane = threadIdx.x & 63;
  const int r16 = lane & 15, g = lane >> 4;
  const int wid = (blockIdx.x * blockDim.x + threadIdx.x) >> 6;
  const int nw = (gridDim.x * blockDim.x) >> 6;

  if (wid == 0) {  // pack W2 into B-frag order (8 KB, once)
#pragma unroll
    for (int ks = 0; ks < 2; ++ks)
#pragma unroll
      for (int c = 0; c < 4; ++c) {
        bf16x8 t;
#pragma unroll
        for (int jj = 0; jj < 8; ++jj)
          t[jj] = (__bf16)W2[(size_t)(32 * ks + 8 * g + jj) * 64 + 16 * c + r16];
        *(bf16x8*)(W2pack + ((size_t)(ks * 4 + c) * 64 + lane) * 8) = t;
      }
  }

  bf16x8 wt[2][4], wb[2][4];
#pragma unroll
  for (int ks = 0; ks < 2; ++ks)
#pragma unroll
    for (int c = 0; c < 4; ++c) {
      bf16x8 t, b;
#pragma unroll
      for (int jj = 0; jj < 8; ++jj) {
        int k = 32 * ks + 8 * g + jj;
        t[jj] = (__bf16)W1[(size_t)k * 64 + 16 * c + r16];
        b[jj] = (__bf16)W1[(size_t)(64 + k) * 64 + 16 * c + r16];
      }
      wt[ks][c] = t; wb[ks][c] = b;
    }
  float b1c[4];
#pragma unroll
  for (int c = 0; c < 4; ++c) b1c[c] = b1[16 * c + r16];

  const int nTiles = (N + 15) >> 4;
  for (int tile = wid; tile < nTiles; tile += nw) {
    const int a0 = tile * 16;
    int arow = a0 + r16; if (arow >= N) arow = N - 1;

    bf16x8 af[2];
#pragma unroll
    for (int ks = 0; ks < 2; ++ks) {
      const float* p = atom_fea + (size_t)arow * 64 + 32 * ks + 8 * g;
      f32x4 x0 = *(const f32x4*)p;
      f32x4 x1 = *(const f32x4*)(p + 4);
      bf16x8 a;
#pragma unroll
      for (int jj = 0; jj < 4; ++jj) { a[jj] = (__bf16)x0[jj]; a[4 + jj] = (__bf16)x1[jj]; }
      af[ks] = a;
    }

    f32x4 uacc[4], yacc[4];
#pragma unroll
    for (int c = 0; c < 4; ++c) { uacc[c] = (f32x4)0.0f; yacc[c] = (f32x4)0.0f; }
#pragma unroll
    for (int ks = 0; ks < 2; ++ks)
#pragma unroll
      for (int c = 0; c < 4; ++c) {
        uacc[c] = __builtin_amdgcn_mfma_f32_16x16x32_bf16(af[ks], wt[ks][c], uacc[c], 0, 0, 0);
        yacc[c] = __builtin_amdgcn_mfma_f32_16x16x32_bf16(af[ks], wb[ks][c], yacc[c], 0, 0, 0);
      }

#pragma unroll
    for (int c = 0; c < 4; ++c)
#pragma unroll
      for (int j = 0; j < 4; ++j) {
        int row = a0 + 4 * g + j;
        if (row < N) {
          Ub[(size_t)row * 64 + 16 * c + r16] = (__bf16)(uacc[c][j] + b1c[c]);
          Yb[(size_t)row * 64 + 16 * c + r16] = (__bf16)yacc[c][j];
        }
      }
  }
}

// ---------------------------------------------------------------------------
// Main fused kernel v6: R9 pipeline + intra-segment Y double-buffer,
// register budget 168 via __launch_bounds__(64,3) (3 waves/SIMD = observed
// residency; no forced spill).
//   pooled = (sum_e w_e H_e) @ W2 + (sum_e w_e) b2
//   w_e = atom_w[nbr_e]*exp(H_e.wg2 + bgp),  wg2 = W2@Wg, bgp = bg + b2.Wg
// Per wave: stride nw over segments. Cross-segment prefetch (bounds 2-ahead,
// U'/residual 1-ahead, tile0 nbr+Y 1-ahead); intra-segment Y prefetched one
// tile ahead so every gather's ~1000cy L3 latency overlaps compute.
// ---------------------------------------------------------------------------
__global__ __launch_bounds__(64, 3)
void fused_pool(const float* __restrict__ atom_w,
                const float* __restrict__ atom_fea,
                const int* __restrict__ nbr_idx,
                const float* __restrict__ W2,
                const float* __restrict__ b2,
                const float* __restrict__ Wg,
                const float* __restrict__ bg,
                const int* __restrict__ row_start,
                const __bf16* __restrict__ Ub,
                const __bf16* __restrict__ Yb,
                const __bf16* __restrict__ W2pack,
                float* __restrict__ out, int N) {
  const int lane = threadIdx.x & 63;
  const int r16 = lane & 15, g = lane >> 4;
  const int wid = blockIdx.x;
  const int nw = gridDim.x;

  // wg2[k] = sum_d W2[k][d]*Wg[d]  (lane holds k = lane)
  float wgl = 0.f;
  {
    const float* w2row = W2 + (size_t)lane * 64;
#pragma unroll
    for (int d = 0; d < 64; ++d) wgl = fmaf(w2row[d], Wg[d], wgl);
  }
  // distribute wg2 into this lane's A-frag k-slots (k = 32ks + 8g + jj)
  f32x2 wg2p[8];
#pragma unroll
  for (int pI = 0; pI < 8; ++pI) {
    const int ks = pI >> 2, jj = (pI & 3) * 2;
    f32x2 t;
    t[0] = __shfl(wgl, 32 * ks + 8 * g + jj);
    t[1] = __shfl(wgl, 32 * ks + 8 * g + jj + 1);
    wg2p[pI] = t;
  }

  // bgp = bg + sum_d b2[d]*Wg[d]
  float tb = b2[lane] * Wg[lane];
#pragma unroll
  for (int off = 1; off < 64; off <<= 1) tb += __shfl_xor(tb, off);
  const float bgp = bg[0] + tb;
  const float b2l = b2[lane];

  int s = wid;
  if (s >= N) return;

  // ---- pipeline state ----
  int curS, curE;               // bounds of s
  int nxtS = 0, nxtE = 0;       // bounds of s+nw
  int nnS = 0, nnE = 0;         // bounds of s+2nw
  u32x4 cu0, cu1; float cxr;    // U' + residual of s
  u32x4 nu0 = {}, nu1 = {}; float nxr = 0.f;    // of s+nw
  u32x4 fy0, fy1; float faw;    // tile-0 Y of s (arrived)
  u32x4 py0 = {}, py1 = {}; float paw = 0.f; int pnb = 0;

  // ---- prologue ----
  curS = row_start[s]; curE = row_start[s + 1];
  cu0 = *(const u32x4*)(Ub + (size_t)s * 64 + 8 * g);
  cu1 = *(const u32x4*)(Ub + (size_t)s * 64 + 32 + 8 * g);
  cxr = atom_fea[(size_t)s * 64 + lane];
  {
    const int e = curS + r16;
    const int nb = (e < curE) ? nbr_idx[e] : 0;
    fy0 = *(const u32x4*)(Yb + ((size_t)nb << 6) + 8 * g);
    fy1 = *(const u32x4*)(Yb + ((size_t)nb << 6) + 32 + 8 * g);
    faw = atom_w[nb];
  }
  if (s + nw < N) {
    nxtS = row_start[s + nw]; nxtE = row_start[s + nw + 1];
    nu0 = *(const u32x4*)(Ub + (size_t)(s + nw) * 64 + 8 * g);
    nu1 = *(const u32x4*)(Ub + (size_t)(s + nw) * 64 + 32 + 8 * g);
    nxr = atom_fea[(size_t)(s + nw) * 64 + lane];
  }

  for (; s < N; s += nw) {
    const int start = curS, end = curE;
    const int s1 = s + nw, s2 = s + 2 * nw;

    // issue bounds for s+2nw (uniform -> scalar loads)
    if (s2 < N) { nnS = row_start[s2]; nnE = row_start[s2 + 1]; }

    // issue tile-0 nbr index for s+nw
    if (s1 < N) {
      const int e = nxtS + r16;
      pnb = (e < nxtE) ? nbr_idx[e] : 0;
    }

    // unpack U' to f32x2 pairs
    f32x2 uf2[8];
#pragma unroll
    for (int pI = 0; pI < 4; ++pI) {
      uf2[pI] = bfpair(cu0[pI]);
      uf2[4 + pI] = bfpair(cu1[pI]);
    }

    f32x2 z2[8];
#pragma unroll
    for (int k = 0; k < 8; ++k) z2[k] = (f32x2)0.0f;
    float wsum = 0.f;

    // intra-segment Y double buffer: tile-1 nbr index
    int nbn = (start + 16 + r16 < end) ? nbr_idx[start + 16 + r16] : 0;
    u32x4 yc0 = fy0, yc1 = fy1; float awc = faw;

    for (int base = start; base < end; base += 16) {
      const bool hasnext = (base + 16) < end;
      // prefetch next tile's Y / aw / next-next nbr
      u32x4 yn0 = {}, yn1 = {}; float awn = 0.f;
      int nbn2 = 0;
      if (hasnext) {
        yn0 = *(const u32x4*)(Yb + ((size_t)nbn << 6) + 8 * g);
        yn1 = *(const u32x4*)(Yb + ((size_t)nbn << 6) + 32 + 8 * g);
        awn = atom_w[nbn];
        nbn2 = (base + 32 + r16 < end) ? nbr_idx[base + 32 + r16] : 0;
      }

      // ---- compute current tile from yc/awc ----
      const bool v = (base + r16) < end;
      f32x2 h2[8];
      f32x2 d2 = (f32x2)0.0f;
#pragma unroll
      for (int pI = 0; pI < 8; ++pI) {
        const u32 yw = (pI < 4) ? yc0[pI] : yc1[pI - 4];
        f32x2 a = uf2[pI] + bfpair(yw);
        f32x2 t = a * 0.01f;
        f32x2 h; h[0] = fmaxf(a[0], t[0]); h[1] = fmaxf(a[1], t[1]);
        h2[pI] = h;
        d2 += h * wg2p[pI];
      }
      float p = d2[0] + d2[1];
      p += __shfl_xor(p, 16);
      p += __shfl_xor(p, 32);
      const float w = v ? awc * __expf(p + bgp) : 0.f;
      wsum += w;
      const f32x2 w2v = {w, w};
#pragma unroll
      for (int k = 0; k < 8; ++k) z2[k] += w2v * h2[k];

      yc0 = yn0; yc1 = yn1; awc = awn; nbn = nbn2;
    }

    // issue next segment's tile-0 Y now; finalize below hides its latency
    if (s1 < N) {
      py0 = *(const u32x4*)(Yb + ((size_t)pnb << 6) + 8 * g);
      py1 = *(const u32x4*)(Yb + ((size_t)pnb << 6) + 32 + 8 * g);
      paw = atom_w[pnb];
    }

    // ---- finalize: pooled = z @ W2 + wsum*b2, then /ssum + residual ----
    bf16x8 zf0, zf1;
#pragma unroll
    for (int pI = 0; pI < 4; ++pI) {
      zf0[2 * pI] = (__bf16)z2[pI][0];
      zf0[2 * pI + 1] = (__bf16)z2[pI][1];
      zf1[2 * pI] = (__bf16)z2[4 + pI][0];
      zf1[2 * pI + 1] = (__bf16)z2[4 + pI][1];
    }

    f32x4 facc[4];
#pragma unroll
    for (int c = 0; c < 4; ++c) facc[c] = (f32x4)0.0f;
#pragma unroll
    for (int c = 0; c < 4; ++c) {
      const bf16x8 wf0 = *(const bf16x8*)(W2pack + ((size_t)(0 * 4 + c) * 64 + lane) * 8);
      const bf16x8 wf1 = *(const bf16x8*)(W2pack + ((size_t)(1 * 4 + c) * 64 + lane) * 8);
      facc[c] = __builtin_amdgcn_mfma_f32_16x16x32_bf16(zf0, wf0, facc[c], 0, 0, 0);
      facc[c] = __builtin_amdgcn_mfma_f32_16x16x32_bf16(zf1, wf1, facc[c], 0, 0, 0);
    }

    float accv[4];
#pragma unroll
    for (int c = 0; c < 4; ++c) {
      float a = (facc[c][0] + facc[c][1]) + (facc[c][2] + facc[c][3]);
      a += __shfl_xor(a, 16);
      a += __shfl_xor(a, 32);
      accv[c] = a;
    }
    float ssum = wsum;
    ssum += __shfl_xor(ssum, 1);
    ssum += __shfl_xor(ssum, 2);
    ssum += __shfl_xor(ssum, 4);
    ssum += __shfl_xor(ssum, 8);

    float val = accv[0];
    val = (g == 1) ? accv[1] : val;
    val = (g == 2) ? accv[2] : val;
    val = (g == 3) ? accv[3] : val;
    val = fmaf(ssum, b2l, val);

    out[(size_t)s * 64 + lane] = val / (ssum + 1e-13f) + cxr;

    // ---- rotate pipeline; issue U'/residual for s+2nw ----
    curS = nxtS; curE = nxtE;
    cu0 = nu0; cu1 = nu1; cxr = nxr;
    nxtS = nnS; nxtE = nnE;
    if (s2 < N) {
      nu0 = *(const u32x4*)(Ub + (size_t)s2 * 64 + 8 * g);
      nu1 = *(const u32x4*)(Ub + (size_t)s2 * 64 + 32 + 8 * g);
      nxr = atom_fea[(size_t)s2 * 64 + lane];
    }
    fy0 = py0; fy1 = py1; faw = paw;
  }
}

extern "C" void kernel_launch(void* const* d_in, const int* in_sizes, int n_in,
                              void* d_out, int out_size, void* d_ws, size_t ws_size,
                              hipStream_t stream) {
  const float* atom_w   = (const float*)d_in[0];
  const float* atom_fea = (const float*)d_in[1];
  const int*   self_idx = (const int*)d_in[2];
  const int*   nbr_idx  = (const int*)d_in[3];
  const float* W1 = (const float*)d_in[4];
  const float* b1 = (const float*)d_in[5];
  const float* W2 = (const float*)d_in[6];
  const float* b2 = (const float*)d_in[7];
  const float* Wg = (const float*)d_in[8];
  const float* bg = (const float*)d_in[9];
  float* out = (float*)d_out;

  const int N = in_sizes[0];   // atom_weights is (N,1)
  const int M = in_sizes[2];   // self_fea_idx is (M,)

  char* ws = (char*)d_ws;
  int* row_start = (int*)ws;
  size_t off = ((size_t)(N + 1) * sizeof(int) + 255) & ~(size_t)255;
  __bf16* W2pack = (__bf16*)(ws + off);
  __bf16* Ub = W2pack + 8 * 64 * 8;          // 8KB pack region
  __bf16* Yb = Ub + (size_t)N * 64;

  hipLaunchKernelGGL(build_row_start, dim3((M + 255) / 256), dim3(256), 0,
                     stream, self_idx, row_start, M, N);
  hipLaunchKernelGGL(precompute_uy, dim3(512), dim3(256), 0, stream,
                     atom_fea, W1, b1, W2, Ub, Yb, W2pack, N);
  hipLaunchKernelGGL(fused_pool, dim3(8192), dim3(64), 0, stream,
                     atom_w, atom_fea, nbr_idx, W2, b2, Wg, bg,
                     row_start, Ub, Yb, W2pack, out, N);
}